// Round 12
// baseline (36.476 us; speedup 1.0000x reference)
//
#include <hip/hip_runtime.h>

// RNNFFT: depth-10 radix-2 butterfly network over last dim (1024).
// v = x; for l = 9..0: y = B_l(w_l * v); v = (l==1) ? y : x + y
// Pairs at level l: (e, e^h), h = 512>>l. Twiddle: bw[OFF[l] + (e & (n_l-1))].
// Mix (lw^T): role-j: y = lw[j][j]*t_self + lw[1-j][j]*t_partner.
//
// R11 (31us): two-layout butterfly. Layout A (e=lane*16+r): levels 9..6 in-lane,
// 5,4 via DPP quad_perm. One LDS transpose. Layout B (e=r*64+lane): levels 3..0
// in-lane. This round: TWO VECTORS PER WAVE as float2 (.x=vec0, .y=vec1) ->
// packed v_pk_*_f32 halves VALU instrs/vector; wave count halves (8192); per-wave
// overheads (bw staging, 30 scalar twiddles, B-twiddle DS reads, transpose)
// amortize 2x. xrB loaded BETWEEN transpose write/read (fills DS latency,
// disjoint live range from xrA). waves_per_eu(4) caps VGPR at 128 = 4 waves/SIMD
// (>128 would halve occupancy; live ~110-125 so cap should not spill).
// All per-element arithmetic identical to r11 (absmax 7e-9 ordering).

constexpr int VECLEN = 1024;

__device__ __forceinline__ int swz(int f) {      // XOR bits[4:2] with bits[7:5]
  return f ^ (((f >> 5) & 7) << 2);              // preserves 16B groups
}

struct f2 { float x, y; };

// A-layout in-lane levels (9..6), lane-uniform twiddles (scalar loads).
template<int L, bool RESL>
__device__ __forceinline__ void level_inlane(f2 (&v)[16], const f2 (&xr)[16],
                                             const float* __restrict__ bw,
                                             const float* __restrict__ lw) {
  constexpr int n = VECLEN >> L;          // 16, 8, 4, 2
  constexpr int h = n >> 1;               // 8, 4, 2, 1
  constexpr int off = 2048 - (2048 >> L); // OFFSETS[L]
  float w[n];
#pragma unroll
  for (int i = 0; i < n; ++i) w[i] = bw[off + i];
  const float l00 = lw[L*4+0], l01 = lw[L*4+1], l10 = lw[L*4+2], l11 = lw[L*4+3];
#pragma unroll
  for (int r = 0; r < 16; ++r) {
    if ((r & h) == 0) {
      const int q = r ^ h;
      const float w0 = w[r & (n-1)], w1 = w[q & (n-1)];
      const float t0x = w0*v[r].x, t0y = w0*v[r].y;
      const float t1x = w1*v[q].x, t1y = w1*v[q].y;
      const float y0x = l00*t0x + l10*t1x, y0y = l00*t0y + l10*t1y;
      const float y1x = l01*t0x + l11*t1x, y1y = l01*t0y + l11*t1y;
      v[r].x = RESL ? xr[r].x + y0x : y0x;  v[r].y = RESL ? xr[r].y + y0y : y0y;
      v[q].x = RESL ? xr[q].x + y1x : y1x;  v[q].y = RESL ? xr[q].y + y1y : y1y;
    }
  }
}

// A-layout DPP cross levels: L=5 -> lane^1 (0xB1), L=4 -> lane^2 (0x4E).
template<int L, bool RESL>
__device__ __forceinline__ void level_dpp(f2 (&v)[16], const f2 (&xr)[16],
                                          const float (&w)[16],
                                          const float* __restrict__ lw, int lane) {
  static_assert(L == 4 || L == 5, "DPP levels only");
  constexpr int ctl = (L == 5) ? 0xB1 : 0x4E;
  const int role = (lane >> (5 - L)) & 1;
  const float l00 = lw[L*4+0], l01 = lw[L*4+1], l10 = lw[L*4+2], l11 = lw[L*4+3];
  const float cs = role ? l11 : l00;      // coeff on own t
  const float cp = role ? l01 : l10;      // coeff on partner t
#pragma unroll
  for (int r = 0; r < 16; ++r) {
    const float tx = w[r] * v[r].x, ty = w[r] * v[r].y;
    const float px = __int_as_float(
        __builtin_amdgcn_update_dpp(0, __float_as_int(tx), ctl, 0xF, 0xF, true));
    const float py = __int_as_float(
        __builtin_amdgcn_update_dpp(0, __float_as_int(ty), ctl, 0xF, 0xF, true));
    const float yx = cs*tx + cp*px, yy = cs*ty + cp*py;   // exact ordering
    v[r].x = RESL ? xr[r].x + yx : yx;
    v[r].y = RESL ? xr[r].y + yy : yy;
  }
}

template<int L>
__device__ __forceinline__ void loadw_A(float (&w)[16], const float* lds_bw, int lane) {
  constexpr int n = VECLEN >> L;
  constexpr int off = 2048 - (2048 >> L);
  const int f0 = off + ((lane * 16) & (n - 1));
#pragma unroll
  for (int k = 0; k < 4; ++k) {
    const float4 f = *reinterpret_cast<const float4*>(lds_bw + swz(f0 + 4*k));
    w[4*k+0]=f.x; w[4*k+1]=f.y; w[4*k+2]=f.z; w[4*k+3]=f.w;
  }
}

// B-layout (e = r*64 + lane) twiddles: nr = n/64 distinct values per lane.
template<int L>
__device__ __forceinline__ void loadw_B(float* w, const float* lds_bw, int lane) {
  constexpr int off = 2048 - (2048 >> L);
  constexpr int nr = (VECLEN >> L) >> 6;   // 16, 8, 4, 2
#pragma unroll
  for (int j = 0; j < nr; ++j)
    w[j] = lds_bw[swz(off + j*64 + lane)];
}

// B-layout in-lane levels (3..0): pair flips r-bit hb = nr/2; twiddle w[r&(nr-1)].
template<int L, bool RESL>
__device__ __forceinline__ void level_B(f2 (&v)[16], const f2 (&xr)[16],
                                        const float* w, const float* __restrict__ lw) {
  constexpr int nr = (VECLEN >> L) >> 6;   // 16, 8, 4, 2
  constexpr int hb = nr >> 1;              // 8, 4, 2, 1
  const float l00 = lw[L*4+0], l01 = lw[L*4+1], l10 = lw[L*4+2], l11 = lw[L*4+3];
#pragma unroll
  for (int r = 0; r < 16; ++r) {
    if ((r & hb) == 0) {
      const int q = r ^ hb;
      const float w0 = w[r & (nr-1)], w1 = w[q & (nr-1)];
      const float t0x = w0*v[r].x, t0y = w0*v[r].y;
      const float t1x = w1*v[q].x, t1y = w1*v[q].y;
      const float y0x = l00*t0x + l10*t1x, y0y = l00*t0y + l10*t1y;
      const float y1x = l01*t0x + l11*t1x, y1y = l01*t0y + l11*t1y;
      v[r].x = RESL ? xr[r].x + y0x : y0x;  v[r].y = RESL ? xr[r].y + y0y : y0y;
      v[q].x = RESL ? xr[q].x + y1x : y1x;  v[q].y = RESL ? xr[q].y + y1y : y1y;
    }
  }
}

__global__ __launch_bounds__(256)
__attribute__((amdgpu_waves_per_eu(4)))
void rnnfft_kernel(const float* __restrict__ x,
                   const float* __restrict__ bw,
                   const float* __restrict__ lw,
                   float* __restrict__ out, int nvec) {
  __shared__ float lds_bw[2048];           // swizzled bw[0..2016)
  __shared__ float tbuf[4][2][1024];       // per-wave, per-vector transpose (32 KB)
  const int t = threadIdx.x;
  const int w4 = t >> 6;
  const int lane = t & 63;
  const int wid = blockIdx.x * 4 + w4;     // wave id; vectors 2*wid, 2*wid+1
  const size_t base = (size_t)wid * (2 * VECLEN);

  // x in layout A for both vectors, packed as f2.
  f2 v[16], xrA[16];
#pragma unroll
  for (int k = 0; k < 4; ++k) {
    const float4 a = *reinterpret_cast<const float4*>(x + base + lane*16 + 4*k);
    const float4 b = *reinterpret_cast<const float4*>(x + base + VECLEN + lane*16 + 4*k);
    xrA[4*k+0] = {a.x, b.x}; xrA[4*k+1] = {a.y, b.y};
    xrA[4*k+2] = {a.z, b.z}; xrA[4*k+3] = {a.w, b.w};
  }

  // Stage bw[0..2016) into LDS (swizzled), once per block.
  if (t < 252) {
    const float4 a = *reinterpret_cast<const float4*>(bw + 8*t);
    const float4 b = *reinterpret_cast<const float4*>(bw + 8*t + 4);
    *reinterpret_cast<float4*>(lds_bw + swz(8*t)) = a;
    *reinterpret_cast<float4*>(lds_bw + swz(8*t+4)) = b;
  }
  __syncthreads();

#pragma unroll
  for (int r = 0; r < 16; ++r) v[r] = xrA[r];

  float wA[16], wB[16];
  loadw_A<5>(wA, lds_bw, lane);
  loadw_A<4>(wB, lds_bw, lane);

  // Layout A: levels 9..6 in-lane, 5 and 4 via DPP.
  level_inlane<9, true>(v, xrA, bw, lw);
  level_inlane<8, true>(v, xrA, bw, lw);
  level_inlane<7, true>(v, xrA, bw, lw);
  level_inlane<6, true>(v, xrA, bw, lw);
  level_dpp<5, true>(v, xrA, wA, lw, lane);
  level_dpp<4, true>(v, xrA, wB, lw, lane);

  // Transpose both vectors A -> B through per-wave LDS (swizzled).
  float* b0 = tbuf[w4][0];
  float* b1 = tbuf[w4][1];
#pragma unroll
  for (int k = 0; k < 4; ++k) {
    float4 fx, fy;
    fx.x = v[4*k+0].x; fx.y = v[4*k+1].x; fx.z = v[4*k+2].x; fx.w = v[4*k+3].x;
    fy.x = v[4*k+0].y; fy.y = v[4*k+1].y; fy.z = v[4*k+2].y; fy.w = v[4*k+3].y;
    *reinterpret_cast<float4*>(b0 + swz(lane*16 + 4*k)) = fx;
    *reinterpret_cast<float4*>(b1 + swz(lane*16 + 4*k)) = fy;
  }

  // Residual in B layout, loaded while the DS writes are in flight (L1/L2 hits,
  // same cachelines as the A loads). Disjoint live range from xrA.
  f2 xrB[16];
#pragma unroll
  for (int r = 0; r < 16; ++r)
    xrB[r] = { x[base + r*64 + lane], x[base + VECLEN + r*64 + lane] };

  float w3[2], w2[4], w1[8], w0[16];
  loadw_B<3>(w3, lds_bw, lane);
  loadw_B<2>(w2, lds_bw, lane);
#pragma unroll
  for (int r = 0; r < 16; ++r)
    v[r] = { b0[swz(r*64 + lane)], b1[swz(r*64 + lane)] };

  // Layout B: levels 3..0 all in-lane (pure VALU).
  level_B<3, true >(v, xrB, w3, lw);
  loadw_B<1>(w1, lds_bw, lane);
  level_B<2, true >(v, xrB, w2, lw);
  loadw_B<0>(w0, lds_bw, lane);
  level_B<1, false>(v, xrB, w1, lw);   // RES[1] = False
  level_B<0, true >(v, xrB, w0, lw);

  // Store both vectors in B-layout: coalesced 256B dword stores.
#pragma unroll
  for (int r = 0; r < 16; ++r) {
    out[base + r*64 + lane] = v[r].x;
    out[base + VECLEN + r*64 + lane] = v[r].y;
  }
}

extern "C" void kernel_launch(void* const* d_in, const int* in_sizes, int n_in,
                              void* d_out, int out_size, void* d_ws, size_t ws_size,
                              hipStream_t stream) {
  const float* x  = (const float*)d_in[0];
  const float* bw = (const float*)d_in[1];
  const float* lw = (const float*)d_in[2];
  float* out = (float*)d_out;
  const int nvec = in_sizes[0] / VECLEN;        // 16384 vectors
  const int nwave = nvec / 2;                   // 8192 waves (2 vectors each)
  const int wpb = 4;                            // waves per block (256 threads)
  const int blocks = (nwave + wpb - 1) / wpb;   // 2048, exact
  rnnfft_kernel<<<blocks, 256, 0, stream>>>(x, bw, lw, out, nvec);
}

// Round 13
// 35.350 us; speedup vs baseline: 1.0318x; 1.0318x over previous
//
#include <hip/hip_runtime.h>

// RNNFFT: depth-10 radix-2 butterfly network over last dim (1024).
// v = x; for l = 9..0: y = B_l(w_l * v); v = (l==1) ? y : x + y
// Pairs at level l: (e, e^h), h = 512>>l. Twiddle: bw[OFF[l] + (e & (n_l-1))].
// Mix (lw^T): role-j: y = lw[j][j]*t_self + lw[1-j][j]*t_partner.
//
// Two-layout butterfly (r11, 31us):
//   Layout A (e=lane*16+r): levels 9..6 in-lane; 5,4 via DPP quad_perm.
//   One per-wave LDS transpose (XOR-swizzled).
//   Layout B (e=r*64+lane): levels 3..0 in-lane; stores coalesced in B.
// R12 post-mortem: f2 (2 vectors/wave) -> ~150-160 live regs, spill, 36.5us.
//   One vector per wave at 16 elems/lane is the register budget. REVERTED.
// This round vs r11: NO lds_bw staging, NO __syncthreads. With two layouts the
// twiddle patterns are cheap straight from global/L1 (bw is 8KB, L1-resident):
//   in-lane levels: lane-uniform -> scalar loads;
//   levels 5/4: dwordx4 hitting only 2/4 distinct 16B segments;
//   B levels: bw[off+j*64+lane] = perfectly coalesced 256B dword loads.
// LDS = 16KB transpose buffer only (10 blocks/CU headroom); kernel barrier-free.
// Per-element arithmetic identical to r11 (absmax 7e-9).

constexpr int VECLEN = 1024;

__device__ __forceinline__ int swz(int f) {      // XOR bits[4:2] with bits[7:5]
  return f ^ (((f >> 5) & 7) << 2);              // preserves 16B groups
}

// A-layout in-lane levels (9..6), lane-uniform twiddles (scalar loads).
template<int L, bool RESL>
__device__ __forceinline__ void level_inlane(float (&v)[16], const float (&xr)[16],
                                             const float* __restrict__ bw,
                                             const float* __restrict__ lw) {
  constexpr int n = VECLEN >> L;          // 16, 8, 4, 2
  constexpr int h = n >> 1;               // 8, 4, 2, 1
  constexpr int off = 2048 - (2048 >> L); // OFFSETS[L]
  float w[n];
#pragma unroll
  for (int i = 0; i < n; ++i) w[i] = bw[off + i];
  const float l00 = lw[L*4+0], l01 = lw[L*4+1], l10 = lw[L*4+2], l11 = lw[L*4+3];
#pragma unroll
  for (int r = 0; r < 16; ++r) {
    if ((r & h) == 0) {
      const int q = r ^ h;
      const float t0 = w[r & (n-1)] * v[r];
      const float t1 = w[q & (n-1)] * v[q];
      const float y0 = l00*t0 + l10*t1;   // role 0 (exact r4/r11 ordering)
      const float y1 = l01*t0 + l11*t1;   // role 1
      v[r] = RESL ? xr[r] + y0 : y0;
      v[q] = RESL ? xr[q] + y1 : y1;
    }
  }
}

// A-layout DPP cross levels: L=5 -> lane^1 (0xB1), L=4 -> lane^2 (0x4E).
template<int L, bool RESL>
__device__ __forceinline__ void level_dpp(float (&v)[16], const float (&xr)[16],
                                          const float (&w)[16],
                                          const float* __restrict__ lw, int lane) {
  static_assert(L == 4 || L == 5, "DPP levels only");
  constexpr int ctl = (L == 5) ? 0xB1 : 0x4E;
  const int role = (lane >> (5 - L)) & 1;
  const float l00 = lw[L*4+0], l01 = lw[L*4+1], l10 = lw[L*4+2], l11 = lw[L*4+3];
  const float cs = role ? l11 : l00;      // coeff on own t
  const float cp = role ? l01 : l10;      // coeff on partner t
#pragma unroll
  for (int r = 0; r < 16; ++r) {
    const float t = w[r] * v[r];
    const float tp = __int_as_float(
        __builtin_amdgcn_update_dpp(0, __float_as_int(t), ctl, 0xF, 0xF, true));
    const float y = cs*t + cp*tp;         // exact ordering
    v[r] = RESL ? xr[r] + y : y;
  }
}

// Levels 5/4 twiddles straight from global: only 2 (L=5) / 4 (L=4) distinct
// 16B segments per dwordx4 -> broadcast-cheap, L1-resident.
template<int L>
__device__ __forceinline__ void loadw_A(float (&w)[16], const float* __restrict__ bw,
                                        int lane) {
  constexpr int n = VECLEN >> L;
  constexpr int off = 2048 - (2048 >> L);
  const int f0 = off + ((lane * 16) & (n - 1));
#pragma unroll
  for (int k = 0; k < 4; ++k) {
    const float4 f = *reinterpret_cast<const float4*>(bw + f0 + 4*k);
    w[4*k+0]=f.x; w[4*k+1]=f.y; w[4*k+2]=f.z; w[4*k+3]=f.w;
  }
}

// B-layout twiddles straight from global: bw[off + j*64 + lane] = coalesced
// 256B per instr, L1-resident.
template<int L>
__device__ __forceinline__ void loadw_B(float* w, const float* __restrict__ bw,
                                        int lane) {
  constexpr int off = 2048 - (2048 >> L);
  constexpr int nr = (VECLEN >> L) >> 6;   // 16, 8, 4, 2
#pragma unroll
  for (int j = 0; j < nr; ++j)
    w[j] = bw[off + j*64 + lane];
}

// B-layout in-lane levels (3..0): pair flips r-bit hb = nr/2; twiddle w[r&(nr-1)].
template<int L, bool RESL>
__device__ __forceinline__ void level_B(float (&v)[16], const float (&xr)[16],
                                        const float* w, const float* __restrict__ lw) {
  constexpr int nr = (VECLEN >> L) >> 6;   // 16, 8, 4, 2
  constexpr int hb = nr >> 1;              // 8, 4, 2, 1
  const float l00 = lw[L*4+0], l01 = lw[L*4+1], l10 = lw[L*4+2], l11 = lw[L*4+3];
#pragma unroll
  for (int r = 0; r < 16; ++r) {
    if ((r & hb) == 0) {
      const int q = r ^ hb;
      const float t0 = w[r & (nr-1)] * v[r];
      const float t1 = w[q & (nr-1)] * v[q];
      const float y0 = l00*t0 + l10*t1;
      const float y1 = l01*t0 + l11*t1;
      v[r] = RESL ? xr[r] + y0 : y0;
      v[q] = RESL ? xr[q] + y1 : y1;
    }
  }
}

__global__ __launch_bounds__(256)
void rnnfft_kernel(const float* __restrict__ x,
                   const float* __restrict__ bw,
                   const float* __restrict__ lw,
                   float* __restrict__ out, int nvec) {
  __shared__ float tbuf[4][1024];          // per-wave transpose buffer (16 KB)
  const int t = threadIdx.x;
  const int w4 = t >> 6;
  const int lane = t & 63;
  const int wid = blockIdx.x * 4 + w4;     // wave id = vector id (grid exact)
  const size_t base = (size_t)wid * VECLEN;

  // x in layout A; twiddles for levels 5/4 prefetched (all global, overlap).
  float v[16], xrA[16];
#pragma unroll
  for (int k = 0; k < 4; ++k) {
    const float4 f = *reinterpret_cast<const float4*>(x + base + lane*16 + 4*k);
    xrA[4*k+0]=f.x; xrA[4*k+1]=f.y; xrA[4*k+2]=f.z; xrA[4*k+3]=f.w;
  }
  float wA[16], wB[16];
  loadw_A<5>(wA, bw, lane);
  loadw_A<4>(wB, bw, lane);

#pragma unroll
  for (int r = 0; r < 16; ++r) v[r] = xrA[r];

  // Layout A: levels 9..6 in-lane, 5 and 4 via DPP.
  level_inlane<9, true>(v, xrA, bw, lw);
  level_inlane<8, true>(v, xrA, bw, lw);
  level_inlane<7, true>(v, xrA, bw, lw);
  level_inlane<6, true>(v, xrA, bw, lw);
  level_dpp<5, true>(v, xrA, wA, lw, lane);
  level_dpp<4, true>(v, xrA, wB, lw, lane);

  // Transpose v: A -> B through per-wave LDS buffer (swizzled). No barrier:
  // per-wave buffer, within-wave DS ordering via lgkmcnt (proven in r11).
  float* buf = tbuf[w4];
#pragma unroll
  for (int k = 0; k < 4; ++k) {
    float4 f;
    f.x = v[4*k+0]; f.y = v[4*k+1]; f.z = v[4*k+2]; f.w = v[4*k+3];
    *reinterpret_cast<float4*>(buf + swz(lane*16 + 4*k)) = f;
  }

  // Residual in B layout (same cachelines as A loads -> L1/L2 hits) and the
  // first B twiddles ride while the DS writes are in flight.
  float xrB[16];
#pragma unroll
  for (int r = 0; r < 16; ++r) xrB[r] = x[base + r*64 + lane];
  float w3[2], w2[4], w1[8], w0[16];
  loadw_B<3>(w3, bw, lane);
  loadw_B<2>(w2, bw, lane);

#pragma unroll
  for (int r = 0; r < 16; ++r) v[r] = buf[swz(r*64 + lane)];

  // Layout B: levels 3..0 all in-lane (pure VALU).
  level_B<3, true >(v, xrB, w3, lw);
  loadw_B<1>(w1, bw, lane);
  level_B<2, true >(v, xrB, w2, lw);
  loadw_B<0>(w0, bw, lane);
  level_B<1, false>(v, xrB, w1, lw);   // RES[1] = False
  level_B<0, true >(v, xrB, w0, lw);

  // Store directly in B-layout: 16 coalesced 256B dword stores.
#pragma unroll
  for (int r = 0; r < 16; ++r) out[base + r*64 + lane] = v[r];
}

extern "C" void kernel_launch(void* const* d_in, const int* in_sizes, int n_in,
                              void* d_out, int out_size, void* d_ws, size_t ws_size,
                              hipStream_t stream) {
  const float* x  = (const float*)d_in[0];
  const float* bw = (const float*)d_in[1];
  const float* lw = (const float*)d_in[2];
  float* out = (float*)d_out;
  const int nvec = in_sizes[0] / VECLEN;        // 16384 vectors
  const int wpb = 4;                            // waves per block (256 threads)
  const int blocks = (nvec + wpb - 1) / wpb;    // 4096, exact
  rnnfft_kernel<<<blocks, 256, 0, stream>>>(x, bw, lw, out, nvec);
}

// Round 14
// 32.730 us; speedup vs baseline: 1.1144x; 1.0800x over previous
//
#include <hip/hip_runtime.h>

// RNNFFT: depth-10 radix-2 butterfly network over last dim (1024).
// v = x; for l = 9..0: y = B_l(w_l * v); v = (l==1) ? y : x + y
// Pairs at level l: (e, e^h), h = 512>>l. Twiddle: bw[OFF[l] + (e & (n_l-1))].
// Mix (lw^T): role-j: y = lw[j][j]*t_self + lw[1-j][j]*t_partner.
//
// Structure (r11 baseline, 31us — best):
//   Layout A (e=lane*16+r): levels 9..6 in-lane; 5,4 via DPP quad_perm.
//   One per-wave LDS transpose (XOR-swizzled). bw staged in LDS (r13: global
//   twiddles regressed +4.3us — VMEM op count matters).
//   Layout B (e=r*64+lane): levels 3..0 in-lane; stores coalesced in B.
// This round: PACKED FP32 along r (float2 = elements 2i,2i+1 of the SAME vector;
// r12's vector-axis packing doubled state and spilled — this keeps 32 VGPRs).
// v_pk_mul/fma_f32 halve VALU instrs. Cross-half levels (A:L9 h=1; B:L3 hb=1)
// mix across the float2 halves with scalar fma; all other levels pair whole
// float2s at i-distance 1/2/4. Per-half arithmetic order identical to r11
// (absmax 7e-9).

constexpr int VECLEN = 1024;

typedef float f32x2 __attribute__((ext_vector_type(2)));

__device__ __forceinline__ f32x2 sp(float a) { return (f32x2){a, a}; }

__device__ __forceinline__ int swz(int f) {      // XOR bits[4:2] with bits[7:5]
  return f ^ (((f >> 5) & 7) << 2);              // preserves 16B groups
}

// ---- A-layout in-lane levels ----
// L9 (h=1): pairs are the two halves of each float2.
template<bool RESL>
__device__ __forceinline__ void level_A9(f32x2 (&v)[8], const f32x2 (&xr)[8],
                                         const float* __restrict__ bw,
                                         const float* __restrict__ lw) {
  constexpr int off = 2046;               // OFFSETS[9]
  const f32x2 w = { bw[off], bw[off + 1] };
  const float l00 = lw[36], l01 = lw[37], l10 = lw[38], l11 = lw[39];
#pragma unroll
  for (int i = 0; i < 8; ++i) {
    const f32x2 t = w * v[i];
    f32x2 y;
    y.x = l00 * t.x + l10 * t.y;          // role 0 (exact r11 ordering)
    y.y = l01 * t.x + l11 * t.y;          // role 1
    v[i] = RESL ? xr[i] + y : y;
  }
}

// L8..L6 (h=2,4,8): i-distance hi = h/2; packed twiddles wq[i & (nw-1)].
template<int L, bool RESL>
__device__ __forceinline__ void level_Ain(f32x2 (&v)[8], const f32x2 (&xr)[8],
                                          const float* __restrict__ bw,
                                          const float* __restrict__ lw) {
  constexpr int n = VECLEN >> L;          // 4, 8, 16
  constexpr int hi = n >> 2;              // 1, 2, 4 (pair distance in i-space)
  constexpr int nw = n >> 1;              // 2, 4, 8 packed twiddles
  constexpr int off = 2048 - (2048 >> L);
  f32x2 w[nw];
#pragma unroll
  for (int j = 0; j < nw; ++j) w[j] = (f32x2){ bw[off + 2*j], bw[off + 2*j + 1] };
  const float l00 = lw[L*4+0], l01 = lw[L*4+1], l10 = lw[L*4+2], l11 = lw[L*4+3];
#pragma unroll
  for (int i = 0; i < 8; ++i) {
    if ((i & hi) == 0) {
      const int q = i ^ hi;
      const f32x2 t0 = w[i & (nw-1)] * v[i];
      const f32x2 t1 = w[q & (nw-1)] * v[q];
      const f32x2 y0 = sp(l00)*t0 + sp(l10)*t1;
      const f32x2 y1 = sp(l01)*t0 + sp(l11)*t1;
      v[i] = RESL ? xr[i] + y0 : y0;
      v[q] = RESL ? xr[q] + y1 : y1;
    }
  }
}

// L5/L4: lane^1 (DPP 0xB1) / lane^2 (DPP 0x4E); per-half DPP, packed arithmetic.
template<int L, bool RESL>
__device__ __forceinline__ void level_dpp(f32x2 (&v)[8], const f32x2 (&xr)[8],
                                          const f32x2 (&w)[8],
                                          const float* __restrict__ lw, int lane) {
  static_assert(L == 4 || L == 5, "DPP levels only");
  constexpr int ctl = (L == 5) ? 0xB1 : 0x4E;
  const int role = (lane >> (5 - L)) & 1;
  const float l00 = lw[L*4+0], l01 = lw[L*4+1], l10 = lw[L*4+2], l11 = lw[L*4+3];
  const float cs = role ? l11 : l00;
  const float cp = role ? l01 : l10;
#pragma unroll
  for (int i = 0; i < 8; ++i) {
    const f32x2 t = w[i] * v[i];
    f32x2 tp;
    tp.x = __int_as_float(
        __builtin_amdgcn_update_dpp(0, __float_as_int(t.x), ctl, 0xF, 0xF, true));
    tp.y = __int_as_float(
        __builtin_amdgcn_update_dpp(0, __float_as_int(t.y), ctl, 0xF, 0xF, true));
    const f32x2 y = sp(cs)*t + sp(cp)*tp;
    v[i] = RESL ? xr[i] + y : y;
  }
}

template<int L>
__device__ __forceinline__ void loadw_A(f32x2 (&w)[8], const float* lds_bw, int lane) {
  constexpr int n = VECLEN >> L;
  constexpr int off = 2048 - (2048 >> L);
  const int f0 = off + ((lane * 16) & (n - 1));
#pragma unroll
  for (int k = 0; k < 4; ++k) {
    const float4 f = *reinterpret_cast<const float4*>(lds_bw + swz(f0 + 4*k));
    w[2*k+0] = (f32x2){ f.x, f.y };
    w[2*k+1] = (f32x2){ f.z, f.w };
  }
}

// ---- B-layout (e = r*64 + lane) ----
// Packed twiddles: wq[j] = { bw[off+(2j)*64+lane], bw[off+(2j+1)*64+lane] }.
template<int L>
__device__ __forceinline__ void loadw_B(f32x2* w, const float* lds_bw, int lane) {
  constexpr int off = 2048 - (2048 >> L);
  constexpr int nw = ((VECLEN >> L) >> 6) >> 1;   // L3:1 L2:2 L1:4 L0:8
#pragma unroll
  for (int j = 0; j < nw; ++j) {
    w[j].x = lds_bw[swz(off + (2*j)     * 64 + lane)];
    w[j].y = lds_bw[swz(off + (2*j + 1) * 64 + lane)];
  }
}

// L3 (hb=1): pairs are the two halves of each float2 (r bit 0).
template<bool RESL>
__device__ __forceinline__ void level_B3(f32x2 (&v)[8], const f32x2 (&xr)[8],
                                         const f32x2 w,
                                         const float* __restrict__ lw) {
  const float l00 = lw[12], l01 = lw[13], l10 = lw[14], l11 = lw[15];
#pragma unroll
  for (int i = 0; i < 8; ++i) {
    const f32x2 t = w * v[i];
    f32x2 y;
    y.x = l00 * t.x + l10 * t.y;
    y.y = l01 * t.x + l11 * t.y;
    v[i] = RESL ? xr[i] + y : y;
  }
}

// L2..L0 (hb=2,4,8): i-distance di = hb/2; twiddle wq[i & (nw-1)].
template<int L, bool RESL>
__device__ __forceinline__ void level_Bin(f32x2 (&v)[8], const f32x2 (&xr)[8],
                                          const f32x2* w,
                                          const float* __restrict__ lw) {
  constexpr int nr = (VECLEN >> L) >> 6;  // 4, 8, 16
  constexpr int di = nr >> 2;             // 1, 2, 4
  constexpr int nw = nr >> 1;             // 2, 4, 8
  const float l00 = lw[L*4+0], l01 = lw[L*4+1], l10 = lw[L*4+2], l11 = lw[L*4+3];
#pragma unroll
  for (int i = 0; i < 8; ++i) {
    if ((i & di) == 0) {
      const int q = i ^ di;
      const f32x2 t0 = w[i & (nw-1)] * v[i];
      const f32x2 t1 = w[q & (nw-1)] * v[q];
      const f32x2 y0 = sp(l00)*t0 + sp(l10)*t1;
      const f32x2 y1 = sp(l01)*t0 + sp(l11)*t1;
      v[i] = RESL ? xr[i] + y0 : y0;
      v[q] = RESL ? xr[q] + y1 : y1;
    }
  }
}

__global__ __launch_bounds__(256)
void rnnfft_kernel(const float* __restrict__ x,
                   const float* __restrict__ bw,
                   const float* __restrict__ lw,
                   float* __restrict__ out, int nvec) {
  __shared__ float lds_bw[2048];           // swizzled bw[0..2016)
  __shared__ float tbuf[4][1024];          // per-wave transpose buffer (16 KB)
  const int t = threadIdx.x;
  const int w4 = t >> 6;
  const int lane = t & 63;
  const int wid = blockIdx.x * 4 + w4;     // wave id = vector id (grid exact)
  const size_t base = (size_t)wid * VECLEN;

  // x in layout A, packed as adjacent-r float2.
  f32x2 v[8], xrA[8];
#pragma unroll
  for (int k = 0; k < 4; ++k) {
    const float4 f = *reinterpret_cast<const float4*>(x + base + lane*16 + 4*k);
    xrA[2*k+0] = (f32x2){ f.x, f.y };
    xrA[2*k+1] = (f32x2){ f.z, f.w };
  }

  // Stage bw[0..2016) into LDS (swizzled), once per block.
  if (t < 252) {
    const float4 a = *reinterpret_cast<const float4*>(bw + 8*t);
    const float4 b = *reinterpret_cast<const float4*>(bw + 8*t + 4);
    *reinterpret_cast<float4*>(lds_bw + swz(8*t)) = a;
    *reinterpret_cast<float4*>(lds_bw + swz(8*t+4)) = b;
  }
  __syncthreads();

#pragma unroll
  for (int i = 0; i < 8; ++i) v[i] = xrA[i];

  f32x2 wA[8], wB[8];
  loadw_A<5>(wA, lds_bw, lane);
  loadw_A<4>(wB, lds_bw, lane);

  // Layout A: levels 9..6 in-lane, 5 and 4 via DPP.
  level_A9 <true>(v, xrA, bw, lw);
  level_Ain<8, true>(v, xrA, bw, lw);
  level_Ain<7, true>(v, xrA, bw, lw);
  level_Ain<6, true>(v, xrA, bw, lw);
  level_dpp<5, true>(v, xrA, wA, lw, lane);
  level_dpp<4, true>(v, xrA, wB, lw, lane);

  // Transpose v: A -> B through per-wave LDS buffer (swizzled, barrier-free:
  // per-wave buffer, within-wave DS ordering via lgkmcnt).
  float* buf = tbuf[w4];
#pragma unroll
  for (int k = 0; k < 4; ++k) {
    float4 f;
    f.x = v[2*k+0].x; f.y = v[2*k+0].y; f.z = v[2*k+1].x; f.w = v[2*k+1].y;
    *reinterpret_cast<float4*>(buf + swz(lane*16 + 4*k)) = f;
  }

  // Residual in B layout (same cachelines as A loads -> cache hits) and the
  // first B twiddles ride while the DS writes are in flight.
  f32x2 xrB[8];
#pragma unroll
  for (int i = 0; i < 8; ++i)
    xrB[i] = (f32x2){ x[base + (2*i)*64 + lane], x[base + (2*i+1)*64 + lane] };
  f32x2 w3[1], w2[2], w1[4], w0[8];
  loadw_B<3>(w3, lds_bw, lane);
  loadw_B<2>(w2, lds_bw, lane);

#pragma unroll
  for (int i = 0; i < 8; ++i)
    v[i] = (f32x2){ buf[swz((2*i)*64 + lane)], buf[swz((2*i+1)*64 + lane)] };

  // Layout B: levels 3..0 all in-lane (pure VALU).
  level_B3 <true >(v, xrB, w3[0], lw);
  loadw_B<1>(w1, lds_bw, lane);
  level_Bin<2, true >(v, xrB, w2, lw);
  loadw_B<0>(w0, lds_bw, lane);
  level_Bin<1, false>(v, xrB, w1, lw);   // RES[1] = False
  level_Bin<0, true >(v, xrB, w0, lw);

  // Store directly in B-layout: 16 coalesced 256B dword stores.
#pragma unroll
  for (int i = 0; i < 8; ++i) {
    out[base + (2*i)*64 + lane]   = v[i].x;
    out[base + (2*i+1)*64 + lane] = v[i].y;
  }
}

extern "C" void kernel_launch(void* const* d_in, const int* in_sizes, int n_in,
                              void* d_out, int out_size, void* d_ws, size_t ws_size,
                              hipStream_t stream) {
  const float* x  = (const float*)d_in[0];
  const float* bw = (const float*)d_in[1];
  const float* lw = (const float*)d_in[2];
  float* out = (float*)d_out;
  const int nvec = in_sizes[0] / VECLEN;        // 16384 vectors
  const int wpb = 4;                            // waves per block (256 threads)
  const int blocks = (nvec + wpb - 1) / wpb;    // 4096, exact
  rnnfft_kernel<<<blocks, 256, 0, stream>>>(x, bw, lw, out, nvec);
}

// Round 15
// 31.120 us; speedup vs baseline: 1.1721x; 1.0517x over previous
//
#include <hip/hip_runtime.h>

// RNNFFT: depth-10 radix-2 butterfly network over last dim (1024).
// v = x; for l = 9..0: y = B_l(w_l * v); v = (l==1) ? y : x + y
// Pairs at level l: (e, e^h), h = 512>>l. Twiddle: bw[OFF[l] + (e & (n_l-1))].
// Mix (lw^T): role-j: y = lw[j][j]*t_self + lw[1-j][j]*t_partner.
//
// Two-layout butterfly (r11 = 31us best):
//   Layout A (e=lane*16+r): levels 9..6 in-lane; 5,4 via DPP quad_perm.
//   Per-wave LDS transpose (XOR-swizzled). bw staged in LDS (r13: global
//   twiddles regressed). Layout B (e=r*64+lane): levels 3..0 in-lane;
//   coalesced B stores. Scalar float state (r14: f32x2 packing neutral-neg).
// This round: SEQUENTIAL PAIR PIPELINE. Each wave does vectors 2w,2w+1:
//   xrB(a) issued at start (phase-A covers its latency; r11 exposed ~a full
//   L2/L3 stall here); xrA(b) issued after transpose-write(a) (covered by
//   phase-B(a), reuses xrA regs); xrB(b) after phase-B(a) (covered by
//   phase-A(b)); staging+barrier amortized 2x; 8192 waves (halved tail).
//   waves_per_eu(3) -> VGPR cap ~168: allocator headroom, no r3-style spill.
// Per-vector arithmetic identical to r11 (absmax 7.45e-9).

constexpr int VECLEN = 1024;

__device__ __forceinline__ int swz(int f) {      // XOR bits[4:2] with bits[7:5]
  return f ^ (((f >> 5) & 7) << 2);              // preserves 16B groups
}

template<int L, bool RESL>
__device__ __forceinline__ void level_inlane(float (&v)[16], const float (&xr)[16],
                                             const float* __restrict__ bw,
                                             const float* __restrict__ lw) {
  constexpr int n = VECLEN >> L;          // 16, 8, 4, 2
  constexpr int h = n >> 1;               // 8, 4, 2, 1
  constexpr int off = 2048 - (2048 >> L); // OFFSETS[L]
  float w[n];                              // lane-uniform -> scalar loads
#pragma unroll
  for (int i = 0; i < n; ++i) w[i] = bw[off + i];
  const float l00 = lw[L*4+0], l01 = lw[L*4+1], l10 = lw[L*4+2], l11 = lw[L*4+3];
#pragma unroll
  for (int r = 0; r < 16; ++r) {
    if ((r & h) == 0) {
      const int q = r ^ h;
      const float t0 = w[r & (n-1)] * v[r];
      const float t1 = w[q & (n-1)] * v[q];
      const float y0 = l00*t0 + l10*t1;   // role 0 (exact r11 ordering)
      const float y1 = l01*t0 + l11*t1;   // role 1
      v[r] = RESL ? xr[r] + y0 : y0;
      v[q] = RESL ? xr[q] + y1 : y1;
    }
  }
}

template<int L, bool RESL>
__device__ __forceinline__ void level_dpp(float (&v)[16], const float (&xr)[16],
                                          const float (&w)[16],
                                          const float* __restrict__ lw, int lane) {
  static_assert(L == 4 || L == 5, "DPP levels only");
  constexpr int ctl = (L == 5) ? 0xB1 : 0x4E;
  const int role = (lane >> (5 - L)) & 1;
  const float l00 = lw[L*4+0], l01 = lw[L*4+1], l10 = lw[L*4+2], l11 = lw[L*4+3];
  const float cs = role ? l11 : l00;
  const float cp = role ? l01 : l10;
#pragma unroll
  for (int r = 0; r < 16; ++r) {
    const float t = w[r] * v[r];
    const float tp = __int_as_float(
        __builtin_amdgcn_update_dpp(0, __float_as_int(t), ctl, 0xF, 0xF, true));
    const float y = cs*t + cp*tp;
    v[r] = RESL ? xr[r] + y : y;
  }
}

template<int L>
__device__ __forceinline__ void loadw_A(float (&w)[16], const float* lds_bw, int lane) {
  constexpr int n = VECLEN >> L;
  constexpr int off = 2048 - (2048 >> L);
  const int f0 = off + ((lane * 16) & (n - 1));
#pragma unroll
  for (int k = 0; k < 4; ++k) {
    const float4 f = *reinterpret_cast<const float4*>(lds_bw + swz(f0 + 4*k));
    w[4*k+0]=f.x; w[4*k+1]=f.y; w[4*k+2]=f.z; w[4*k+3]=f.w;
  }
}

template<int L>
__device__ __forceinline__ void loadw_B(float* w, const float* lds_bw, int lane) {
  constexpr int off = 2048 - (2048 >> L);
  constexpr int nr = (VECLEN >> L) >> 6;   // 16, 8, 4, 2
#pragma unroll
  for (int j = 0; j < nr; ++j)
    w[j] = lds_bw[swz(off + j*64 + lane)];
}

template<int L, bool RESL>
__device__ __forceinline__ void level_B(float (&v)[16], const float (&xr)[16],
                                        const float* w, const float* __restrict__ lw) {
  constexpr int nr = (VECLEN >> L) >> 6;   // 16, 8, 4, 2
  constexpr int hb = nr >> 1;              // 8, 4, 2, 1
  const float l00 = lw[L*4+0], l01 = lw[L*4+1], l10 = lw[L*4+2], l11 = lw[L*4+3];
#pragma unroll
  for (int r = 0; r < 16; ++r) {
    if ((r & hb) == 0) {
      const int q = r ^ hb;
      const float t0 = w[r & (nr-1)] * v[r];
      const float t1 = w[q & (nr-1)] * v[q];
      const float y0 = l00*t0 + l10*t1;
      const float y1 = l01*t0 + l11*t1;
      v[r] = RESL ? xr[r] + y0 : y0;
      v[q] = RESL ? xr[q] + y1 : y1;
    }
  }
}

// Phase A: levels 9..4 in layout A (twiddles for 5/4 from LDS just-in-time).
__device__ __forceinline__ void phaseA(float (&v)[16], const float (&xrA)[16],
                                       const float* lds_bw,
                                       const float* __restrict__ bw,
                                       const float* __restrict__ lw, int lane) {
  float wA[16], wB[16];
  loadw_A<5>(wA, lds_bw, lane);
  loadw_A<4>(wB, lds_bw, lane);
  level_inlane<9, true>(v, xrA, bw, lw);
  level_inlane<8, true>(v, xrA, bw, lw);
  level_inlane<7, true>(v, xrA, bw, lw);
  level_inlane<6, true>(v, xrA, bw, lw);
  level_dpp<5, true>(v, xrA, wA, lw, lane);
  level_dpp<4, true>(v, xrA, wB, lw, lane);
}

// Phase B: levels 3..0 in layout B (twiddles from LDS just-in-time).
__device__ __forceinline__ void phaseB(float (&v)[16], const float (&xrB)[16],
                                       const float* lds_bw,
                                       const float* __restrict__ lw, int lane) {
  float w3[2], w2[4], w1[8], w0[16];
  loadw_B<3>(w3, lds_bw, lane);
  loadw_B<2>(w2, lds_bw, lane);
  level_B<3, true >(v, xrB, w3, lw);
  loadw_B<1>(w1, lds_bw, lane);
  level_B<2, true >(v, xrB, w2, lw);
  loadw_B<0>(w0, lds_bw, lane);
  level_B<1, false>(v, xrB, w1, lw);   // RES[1] = False
  level_B<0, true >(v, xrB, w0, lw);
}

__device__ __forceinline__ void loadX_A(float (&xr)[16], const float* __restrict__ x,
                                        size_t base, int lane) {
#pragma unroll
  for (int k = 0; k < 4; ++k) {
    const float4 f = *reinterpret_cast<const float4*>(x + base + lane*16 + 4*k);
    xr[4*k+0]=f.x; xr[4*k+1]=f.y; xr[4*k+2]=f.z; xr[4*k+3]=f.w;
  }
}

__device__ __forceinline__ void loadX_B(float (&xr)[16], const float* __restrict__ x,
                                        size_t base, int lane) {
#pragma unroll
  for (int r = 0; r < 16; ++r) xr[r] = x[base + r*64 + lane];
}

__global__ __launch_bounds__(256)
__attribute__((amdgpu_waves_per_eu(3)))
void rnnfft_kernel(const float* __restrict__ x,
                   const float* __restrict__ bw,
                   const float* __restrict__ lw,
                   float* __restrict__ out, int nvec) {
  __shared__ float lds_bw[2048];           // swizzled bw[0..2016)
  __shared__ float tbuf[4][1024];          // per-wave transpose buffer (16 KB)
  const int t = threadIdx.x;
  const int w4 = t >> 6;
  const int lane = t & 63;
  const int wid = blockIdx.x * 4 + w4;     // wave id; vectors 2*wid, 2*wid+1
  const size_t baseA = (size_t)(2 * wid) * VECLEN;
  const size_t baseB = baseA + VECLEN;
  float* buf = tbuf[w4];

  // Issue ALL of vector a's loads up front: xrA(a) and xrB(a). xrB's latency
  // is covered by phase A (r11 exposed this stall).
  float v[16], xrA[16], xrB[16];
  loadX_A(xrA, x, baseA, lane);
  loadX_B(xrB, x, baseA, lane);

  // Stage bw[0..2016) into LDS (swizzled), once per block.
  if (t < 252) {
    const float4 a = *reinterpret_cast<const float4*>(bw + 8*t);
    const float4 b = *reinterpret_cast<const float4*>(bw + 8*t + 4);
    *reinterpret_cast<float4*>(lds_bw + swz(8*t)) = a;
    *reinterpret_cast<float4*>(lds_bw + swz(8*t+4)) = b;
  }
  __syncthreads();

  // ---- vector a ----
#pragma unroll
  for (int r = 0; r < 16; ++r) v[r] = xrA[r];
  phaseA(v, xrA, lds_bw, bw, lw, lane);

#pragma unroll
  for (int k = 0; k < 4; ++k) {
    float4 f;
    f.x = v[4*k+0]; f.y = v[4*k+1]; f.z = v[4*k+2]; f.w = v[4*k+3];
    *reinterpret_cast<float4*>(buf + swz(lane*16 + 4*k)) = f;
  }
  // xrA(a) is dead -> issue vector b's A-layout loads into the same regs;
  // covered by phase B(a) + stores(a).
  loadX_A(xrA, x, baseB, lane);

#pragma unroll
  for (int r = 0; r < 16; ++r) v[r] = buf[swz(r*64 + lane)];
  phaseB(v, xrB, lds_bw, lw, lane);
#pragma unroll
  for (int r = 0; r < 16; ++r) out[baseA + r*64 + lane] = v[r];

  // xrB(a) dead -> issue vector b's B-layout loads; covered by phase A(b).
  loadX_B(xrB, x, baseB, lane);

  // ---- vector b ----
#pragma unroll
  for (int r = 0; r < 16; ++r) v[r] = xrA[r];
  phaseA(v, xrA, lds_bw, bw, lw, lane);

#pragma unroll
  for (int k = 0; k < 4; ++k) {
    float4 f;
    f.x = v[4*k+0]; f.y = v[4*k+1]; f.z = v[4*k+2]; f.w = v[4*k+3];
    *reinterpret_cast<float4*>(buf + swz(lane*16 + 4*k)) = f;
  }
#pragma unroll
  for (int r = 0; r < 16; ++r) v[r] = buf[swz(r*64 + lane)];
  phaseB(v, xrB, lds_bw, lw, lane);
#pragma unroll
  for (int r = 0; r < 16; ++r) out[baseB + r*64 + lane] = v[r];
}

extern "C" void kernel_launch(void* const* d_in, const int* in_sizes, int n_in,
                              void* d_out, int out_size, void* d_ws, size_t ws_size,
                              hipStream_t stream) {
  const float* x  = (const float*)d_in[0];
  const float* bw = (const float*)d_in[1];
  const float* lw = (const float*)d_in[2];
  float* out = (float*)d_out;
  const int nvec = in_sizes[0] / VECLEN;        // 16384 vectors
  const int nwave = nvec / 2;                   // 8192 waves (2 vectors each)
  const int wpb = 4;                            // waves per block (256 threads)
  const int blocks = (nwave + wpb - 1) / wpb;   // 2048, exact
  rnnfft_kernel<<<blocks, 256, 0, stream>>>(x, bw, lw, out, nvec);
}